// Round 2
// baseline (253.871 us; speedup 1.0000x reference)
//
#include <hip/hip_runtime.h>

#define GX 500
#define GY 500
#define GZ 50
#define NCOL (GX * GY)

typedef unsigned long long u64;

__global__ void zero_grid_kernel(u64* __restrict__ g, int n) {
    int i = blockIdx.x * blockDim.x + threadIdx.x;
    if (i < n) g[i] = 0ull;
}

__device__ __forceinline__ bool voxel_of(float px, float py, float pz,
                                         float mnx, float mny, float mnz,
                                         float vs, int& ix, int& iy, int& iz) {
    // Mirror reference exactly: vif = (p - aabb_min) / voxel_size  (f32 division)
    float vx = (px - mnx) / vs;
    float vy = (py - mny) / vs;
    float vz = (pz - mnz) / vs;
    bool in = (vx >= 0.0f) & (vx <= (float)(GX - 1)) &
              (vy >= 0.0f) & (vy <= (float)(GY - 1)) &
              (vz >= 0.0f) & (vz <= (float)(GZ - 1));
    // truncation == floor for non-negative; invalid lanes don't use the index
    ix = (int)vx; iy = (int)vy; iz = (int)vz;
    return in;
}

__global__ void scatter_kernel(const float* __restrict__ pts, int n,
                               const float* __restrict__ aabb,
                               const float* __restrict__ vs_p,
                               u64* __restrict__ grid) {
    int i = blockIdx.x * blockDim.x + threadIdx.x;
    if (i >= n) return;
    const float vs = vs_p[0];
    const float mnx = aabb[0], mny = aabb[1], mnz = aabb[2];
    float px = pts[3 * i + 0];
    float py = pts[3 * i + 1];
    float pz = pts[3 * i + 2];
    int ix, iy, iz;
    bool in = voxel_of(px, py, pz, mnx, mny, mnz, vs, ix, iy, iz);
    if (!in) return;
    atomicOr(&grid[ix * GY + iy], 1ull << iz);
}

__global__ void dilate_kernel(const u64* __restrict__ gin, u64* __restrict__ gout) {
    int i = blockIdx.x * blockDim.x + threadIdx.x;
    if (i >= NCOL) return;
    int ix = i / GY;
    int iy = i - ix * GY;
    int x0 = ix > 0 ? ix - 1 : 0, x1 = ix < GX - 1 ? ix + 1 : GX - 1;
    int y0 = iy > 0 ? iy - 1 : 0, y1 = iy < GY - 1 ? iy + 1 : GY - 1;
    u64 acc = 0ull;
    for (int x = x0; x <= x1; ++x)
        for (int y = y0; y <= y1; ++y)
            acc |= gin[x * GY + y];
    // z-dilation: bits >= GZ never queried (z index <= 49), shifts are safe
    acc = acc | (acc << 1) | (acc >> 1);
    gout[i] = acc;
}

__global__ void query_kernel(const float* __restrict__ q, int n,
                             const float* __restrict__ aabb,
                             const float* __restrict__ vs_p,
                             const u64* __restrict__ grid,
                             int* __restrict__ out) {
    int i = blockIdx.x * blockDim.x + threadIdx.x;
    if (i >= n) return;
    const float vs = vs_p[0];
    const float mnx = aabb[0], mny = aabb[1], mnz = aabb[2];
    float px = q[3 * i + 0];
    float py = q[3 * i + 1];
    float pz = q[3 * i + 2];
    int ix, iy, iz;
    bool in = voxel_of(px, py, pz, mnx, mny, mnz, vs, ix, iy, iz);
    bool occ = false;
    if (in) occ = (grid[ix * GY + iy] >> iz) & 1ull;
    out[i] = occ ? 1 : 0;
}

extern "C" void kernel_launch(void* const* d_in, const int* in_sizes, int n_in,
                              void* d_out, int out_size, void* d_ws, size_t ws_size,
                              hipStream_t stream) {
    const float* points = (const float*)d_in[0];
    const float* query  = (const float*)d_in[1];
    const float* aabb   = (const float*)d_in[2];
    const float* vs     = (const float*)d_in[3];
    int* out = (int*)d_out;

    int n_pts = in_sizes[0] / 3;
    int n_q   = in_sizes[1] / 3;

    u64* grid    = (u64*)d_ws;                       // 2 MB
    u64* dilated = (u64*)((char*)d_ws + NCOL * 8);   // 2 MB

    const int B = 256;
    zero_grid_kernel<<<(NCOL + B - 1) / B, B, 0, stream>>>(grid, NCOL);
    scatter_kernel<<<(n_pts + B - 1) / B, B, 0, stream>>>(points, n_pts, aabb, vs, grid);
    dilate_kernel<<<(NCOL + B - 1) / B, B, 0, stream>>>(grid, dilated);
    query_kernel<<<(n_q + B - 1) / B, B, 0, stream>>>(query, n_q, aabb, vs, dilated, out);
}

// Round 3
// 120.570 us; speedup vs baseline: 2.1056x; 2.1056x over previous
//
#include <hip/hip_runtime.h>

#define GX 500
#define GY 500
#define GZ 50
#define NCOL (GX * GY)
#define ZPAD 64
#define BG_BYTES ((size_t)NCOL * ZPAD)   // 16,000,000 bytes

typedef unsigned long long u64;

__device__ __forceinline__ bool voxel_of(float px, float py, float pz,
                                         float mnx, float mny, float mnz,
                                         float vs, int& ix, int& iy, int& iz) {
    // Mirror reference exactly: vif = (p - aabb_min) / voxel_size (IEEE f32 div)
    float vx = (px - mnx) / vs;
    float vy = (py - mny) / vs;
    float vz = (pz - mnz) / vs;
    bool in = (vx >= 0.0f) & (vx <= (float)(GX - 1)) &
              (vy >= 0.0f) & (vy <= (float)(GY - 1)) &
              (vz >= 0.0f) & (vz <= (float)(GZ - 1));
    ix = (int)vx; iy = (int)vy; iz = (int)vz;  // trunc == floor for non-negative
    return in;
}

// ---------------- byte-grid (store) path ----------------

__global__ void zero_bytes_kernel(ulonglong2* __restrict__ g, int n16) {
    int i = blockIdx.x * blockDim.x + threadIdx.x;
    if (i < n16) g[i] = make_ulonglong2(0ull, 0ull);
}

__global__ void scatter_bytes_kernel(const float* __restrict__ pts, int n,
                                     const float* __restrict__ aabb,
                                     const float* __restrict__ vs_p,
                                     unsigned char* __restrict__ bg) {
    int t = blockIdx.x * blockDim.x + threadIdx.x;
    int base = t * 4;
    if (base >= n) return;
    const float vs = vs_p[0];
    const float mnx = aabb[0], mny = aabb[1], mnz = aabb[2];
    float x[4], y[4], z[4];
    int cnt;
    if (base + 4 <= n) {
        const float4* p4 = (const float4*)pts + 3 * t;   // 48B/thread, coalesced
        float4 a = p4[0], b = p4[1], c = p4[2];
        x[0] = a.x; y[0] = a.y; z[0] = a.z;
        x[1] = a.w; y[1] = b.x; z[1] = b.y;
        x[2] = b.z; y[2] = b.w; z[2] = c.x;
        x[3] = c.y; y[3] = c.z; z[3] = c.w;
        cnt = 4;
    } else {
        cnt = n - base;
        for (int k = 0; k < cnt; ++k) {
            x[k] = pts[3 * (base + k) + 0];
            y[k] = pts[3 * (base + k) + 1];
            z[k] = pts[3 * (base + k) + 2];
        }
    }
    #pragma unroll
    for (int k = 0; k < 4; ++k) {
        if (k >= cnt) break;
        int ix, iy, iz;
        if (voxel_of(x[k], y[k], z[k], mnx, mny, mnz, vs, ix, iy, iz))
            bg[(size_t)(ix * GY + iy) * ZPAD + iz] = (unsigned char)1;  // benign race
    }
}

__global__ void pack_kernel(const u64* __restrict__ bg, u64* __restrict__ grid) {
    int col = blockIdx.x * blockDim.x + threadIdx.x;
    if (col >= NCOL) return;
    const u64* w = bg + (size_t)col * 8;   // 64 bytes, cacheline-aligned
    u64 bits = 0ull;
    #pragma unroll
    for (int k = 0; k < 8; ++k) {
        u64 v = w[k];  // bytes are 0x00 or 0x01
        bits |= ((v * 0x0102040810204080ull) >> 56) << (8 * k);
    }
    grid[col] = bits;
}

// ---------------- atomic fallback path ----------------

__global__ void zero_grid_kernel(u64* __restrict__ g, int n) {
    int i = blockIdx.x * blockDim.x + threadIdx.x;
    if (i < n) g[i] = 0ull;
}

__global__ void scatter_atomic_kernel(const float* __restrict__ pts, int n,
                                      const float* __restrict__ aabb,
                                      const float* __restrict__ vs_p,
                                      u64* __restrict__ grid) {
    int i = blockIdx.x * blockDim.x + threadIdx.x;
    if (i >= n) return;
    const float vs = vs_p[0];
    const float mnx = aabb[0], mny = aabb[1], mnz = aabb[2];
    int ix, iy, iz;
    if (voxel_of(pts[3 * i], pts[3 * i + 1], pts[3 * i + 2],
                 mnx, mny, mnz, vs, ix, iy, iz))
        atomicOr(&grid[ix * GY + iy], 1ull << iz);
}

// ---------------- shared tail ----------------

__global__ void dilate_kernel(const u64* __restrict__ gin, u64* __restrict__ gout) {
    int i = blockIdx.x * blockDim.x + threadIdx.x;
    if (i >= NCOL) return;
    int ix = i / GY;
    int iy = i - ix * GY;
    int x0 = ix > 0 ? ix - 1 : 0, x1 = ix < GX - 1 ? ix + 1 : GX - 1;
    int y0 = iy > 0 ? iy - 1 : 0, y1 = iy < GY - 1 ? iy + 1 : GY - 1;
    u64 acc = 0ull;
    for (int x = x0; x <= x1; ++x)
        for (int y = y0; y <= y1; ++y)
            acc |= gin[x * GY + y];
    acc = acc | (acc << 1) | (acc >> 1);   // z-dilation; bits >= 50 never queried
    gout[i] = acc;
}

__global__ void query4_kernel(const float* __restrict__ q, int n,
                              const float* __restrict__ aabb,
                              const float* __restrict__ vs_p,
                              const u64* __restrict__ grid,
                              int* __restrict__ out) {
    int t = blockIdx.x * blockDim.x + threadIdx.x;
    int base = t * 4;
    if (base >= n) return;
    const float vs = vs_p[0];
    const float mnx = aabb[0], mny = aabb[1], mnz = aabb[2];
    float x[4], y[4], z[4];
    int cnt;
    if (base + 4 <= n) {
        const float4* p4 = (const float4*)q + 3 * t;
        float4 a = p4[0], b = p4[1], c = p4[2];
        x[0] = a.x; y[0] = a.y; z[0] = a.z;
        x[1] = a.w; y[1] = b.x; z[1] = b.y;
        x[2] = b.z; y[2] = b.w; z[2] = c.x;
        x[3] = c.y; y[3] = c.z; z[3] = c.w;
        cnt = 4;
    } else {
        cnt = n - base;
        for (int k = 0; k < cnt; ++k) {
            x[k] = q[3 * (base + k) + 0];
            y[k] = q[3 * (base + k) + 1];
            z[k] = q[3 * (base + k) + 2];
        }
    }
    int r[4] = {0, 0, 0, 0};
    #pragma unroll
    for (int k = 0; k < 4; ++k) {
        if (k >= cnt) break;
        int ix, iy, iz;
        if (voxel_of(x[k], y[k], z[k], mnx, mny, mnz, vs, ix, iy, iz))
            r[k] = (int)((grid[ix * GY + iy] >> iz) & 1ull);
    }
    if (cnt == 4) ((int4*)out)[t] = make_int4(r[0], r[1], r[2], r[3]);
    else for (int k = 0; k < cnt; ++k) out[base + k] = r[k];
}

extern "C" void kernel_launch(void* const* d_in, const int* in_sizes, int n_in,
                              void* d_out, int out_size, void* d_ws, size_t ws_size,
                              hipStream_t stream) {
    const float* points = (const float*)d_in[0];
    const float* query  = (const float*)d_in[1];
    const float* aabb   = (const float*)d_in[2];
    const float* vs     = (const float*)d_in[3];
    int* out = (int*)d_out;

    int n_pts = in_sizes[0] / 3;
    int n_q   = in_sizes[1] / 3;
    const int B = 256;

    size_t need = BG_BYTES + 2 * (size_t)NCOL * 8;   // 20 MB
    if (ws_size >= need) {
        unsigned char* bg = (unsigned char*)d_ws;
        u64* grid    = (u64*)((char*)d_ws + BG_BYTES);
        u64* dilated = grid + NCOL;

        int n16 = (int)(BG_BYTES / 16);
        int n_sc = (n_pts + 3) / 4;
        int n_qt = (n_q + 3) / 4;
        zero_bytes_kernel<<<(n16 + B - 1) / B, B, 0, stream>>>((ulonglong2*)bg, n16);
        scatter_bytes_kernel<<<(n_sc + B - 1) / B, B, 0, stream>>>(points, n_pts, aabb, vs, bg);
        pack_kernel<<<(NCOL + B - 1) / B, B, 0, stream>>>((const u64*)bg, grid);
        dilate_kernel<<<(NCOL + B - 1) / B, B, 0, stream>>>(grid, dilated);
        query4_kernel<<<(n_qt + B - 1) / B, B, 0, stream>>>(query, n_q, aabb, vs, dilated, out);
    } else {
        // fallback: proven atomic path (needs 4 MB)
        u64* grid    = (u64*)d_ws;
        u64* dilated = grid + NCOL;
        int n_qt = (n_q + 3) / 4;
        zero_grid_kernel<<<(NCOL + B - 1) / B, B, 0, stream>>>(grid, NCOL);
        scatter_atomic_kernel<<<(n_pts + B - 1) / B, B, 0, stream>>>(points, n_pts, aabb, vs, grid);
        dilate_kernel<<<(NCOL + B - 1) / B, B, 0, stream>>>(grid, dilated);
        query4_kernel<<<(n_qt + B - 1) / B, B, 0, stream>>>(query, n_q, aabb, vs, dilated, out);
    }
}

// Round 4
// 101.161 us; speedup vs baseline: 2.5096x; 1.1919x over previous
//
#include <hip/hip_runtime.h>

#define GX 500
#define GY 500
#define GZ 50
#define NCOL (GX * GY)

#define CAP_R 7936                       // entries per bucket-replica segment
#define NSEG (GX * 2)                    // 500 x-buckets x 2 replicas
#define TOT_ENTRIES ((unsigned)CAP_R * NSEG)  // 7,936,000
#define PTS_PER_BLOCK 8192

typedef unsigned long long u64;
typedef unsigned int u32;
typedef unsigned short u16;

__device__ __forceinline__ bool voxel_of(float px, float py, float pz,
                                         float mnx, float mny, float mnz,
                                         float vs, int& ix, int& iy, int& iz) {
    // Mirror reference exactly: vif = (p - aabb_min) / voxel_size (IEEE f32 div)
    float vx = (px - mnx) / vs;
    float vy = (py - mny) / vs;
    float vz = (pz - mnz) / vs;
    bool in = (vx >= 0.0f) & (vx <= (float)(GX - 1)) &
              (vy >= 0.0f) & (vy <= (float)(GY - 1)) &
              (vz >= 0.0f) & (vz <= (float)(GZ - 1));
    ix = (int)vx; iy = (int)vy; iz = (int)vz;  // trunc == floor for non-negative
    return in;
}

// ---------------- binned scatter path ----------------

__global__ void zero_tails_kernel(u32* __restrict__ tails) {
    for (int i = threadIdx.x; i < NSEG; i += 256) tails[i] = 0;
}

__global__ __launch_bounds__(256) void scatter_bin_kernel(
    const float* __restrict__ pts, int n,
    const float* __restrict__ aabb, const float* __restrict__ vs_p,
    u16* __restrict__ buf, u32* __restrict__ tails)
{
    __shared__ u32 hist[GX];
    __shared__ u32 base[GX];
    const int tid = threadIdx.x;
    for (int b = tid; b < GX; b += 256) hist[b] = 0;
    __syncthreads();

    const float vs = vs_p[0];
    const float mnx = aabb[0], mny = aabb[1], mnz = aabb[2];
    const int blk = blockIdx.x;
    const u32 rep = (u32)(blk & 1);
    const int p0 = blk * PTS_PER_BLOCK;

    u32 vid[32];   // packed (x<<15 | y<<6 | z), 0xFFFFFFFF = invalid
    u32 ofs[32];

    #pragma unroll
    for (int s = 0; s < 8; ++s) {
        int gbase = p0 + s * 1024 + tid * 4;
        float x[4], y[4], z[4];
        int cnt = 0;
        if (gbase + 4 <= n) {
            const float4* p4 = (const float4*)pts + (size_t)(gbase >> 2) * 3;
            float4 a = p4[0], b4 = p4[1], c = p4[2];
            x[0] = a.x;  y[0] = a.y;  z[0] = a.z;
            x[1] = a.w;  y[1] = b4.x; z[1] = b4.y;
            x[2] = b4.z; y[2] = b4.w; z[2] = c.x;
            x[3] = c.y;  y[3] = c.z;  z[3] = c.w;
            cnt = 4;
        } else if (gbase < n) {
            cnt = n - gbase;
            for (int k = 0; k < cnt; ++k) {
                x[k] = pts[3 * (gbase + k) + 0];
                y[k] = pts[3 * (gbase + k) + 1];
                z[k] = pts[3 * (gbase + k) + 2];
            }
        }
        #pragma unroll
        for (int k = 0; k < 4; ++k) {
            int j = s * 4 + k;
            vid[j] = 0xFFFFFFFFu;
            if (k < cnt) {
                int ix, iy, iz;
                if (voxel_of(x[k], y[k], z[k], mnx, mny, mnz, vs, ix, iy, iz)) {
                    vid[j] = ((u32)ix << 15) | ((u32)iy << 6) | (u32)iz;
                    ofs[j] = atomicAdd(&hist[ix], 1u);
                }
            }
        }
    }
    __syncthreads();
    for (int b = tid; b < GX; b += 256) {
        u32 h = hist[b];
        base[b] = h ? atomicAdd(&tails[b * 2 + rep], h) : 0u;
    }
    __syncthreads();
    #pragma unroll
    for (int j = 0; j < 32; ++j) {
        u32 v = vid[j];
        if (v != 0xFFFFFFFFu) {
            u32 bx = v >> 15;
            u32 idx = (bx * 2u + rep) * (u32)CAP_R + base[bx] + ofs[j];
            if (idx < TOT_ENTRIES) buf[idx] = (u16)(v & 0x7FFFu);
        }
    }
}

__global__ __launch_bounds__(256) void replay_kernel(
    const u16* __restrict__ buf, const u32* __restrict__ tails,
    u64* __restrict__ grid)
{
    __shared__ u32 col[GY * 2];
    const int x = blockIdx.x;
    const int tid = threadIdx.x;
    for (int i = tid; i < GY * 2; i += 256) col[i] = 0;
    __syncthreads();
    #pragma unroll
    for (int r = 0; r < 2; ++r) {
        u32 cnt = tails[x * 2 + r];
        if (cnt > (u32)CAP_R) cnt = (u32)CAP_R;
        const u16* seg = buf + (size_t)(x * 2 + r) * CAP_R;
        for (u32 i = tid; i < cnt; i += 256) {
            u32 e = seg[i];
            u32 y = e >> 6, z = e & 63u;
            atomicOr(&col[y * 2 + (z >> 5)], 1u << (z & 31u));
        }
    }
    __syncthreads();
    for (int y = tid; y < GY; y += 256)
        grid[x * GY + y] = (u64)col[y * 2] | ((u64)col[y * 2 + 1] << 32);
}

// ---------------- atomic fallback path (small ws) ----------------

__global__ void zero_grid_kernel(u64* __restrict__ g, int n) {
    int i = blockIdx.x * blockDim.x + threadIdx.x;
    if (i < n) g[i] = 0ull;
}

__global__ void scatter_atomic_kernel(const float* __restrict__ pts, int n,
                                      const float* __restrict__ aabb,
                                      const float* __restrict__ vs_p,
                                      u64* __restrict__ grid) {
    int i = blockIdx.x * blockDim.x + threadIdx.x;
    if (i >= n) return;
    const float vs = vs_p[0];
    const float mnx = aabb[0], mny = aabb[1], mnz = aabb[2];
    int ix, iy, iz;
    if (voxel_of(pts[3 * i], pts[3 * i + 1], pts[3 * i + 2],
                 mnx, mny, mnz, vs, ix, iy, iz))
        atomicOr(&grid[ix * GY + iy], 1ull << iz);
}

// ---------------- shared tail ----------------

__global__ void dilate_kernel(const u64* __restrict__ gin, u64* __restrict__ gout) {
    int i = blockIdx.x * blockDim.x + threadIdx.x;
    if (i >= NCOL) return;
    int ix = i / GY;
    int iy = i - ix * GY;
    int x0 = ix > 0 ? ix - 1 : 0, x1 = ix < GX - 1 ? ix + 1 : GX - 1;
    int y0 = iy > 0 ? iy - 1 : 0, y1 = iy < GY - 1 ? iy + 1 : GY - 1;
    u64 acc = 0ull;
    for (int x = x0; x <= x1; ++x)
        for (int y = y0; y <= y1; ++y)
            acc |= gin[x * GY + y];
    acc = acc | (acc << 1) | (acc >> 1);   // z-dilation; bits >= 50 never queried
    gout[i] = acc;
}

__global__ void query4_kernel(const float* __restrict__ q, int n,
                              const float* __restrict__ aabb,
                              const float* __restrict__ vs_p,
                              const u64* __restrict__ grid,
                              int* __restrict__ out) {
    int t = blockIdx.x * blockDim.x + threadIdx.x;
    int base = t * 4;
    if (base >= n) return;
    const float vs = vs_p[0];
    const float mnx = aabb[0], mny = aabb[1], mnz = aabb[2];
    float x[4], y[4], z[4];
    int cnt;
    if (base + 4 <= n) {
        const float4* p4 = (const float4*)q + 3 * t;
        float4 a = p4[0], b = p4[1], c = p4[2];
        x[0] = a.x;  y[0] = a.y;  z[0] = a.z;
        x[1] = a.w;  y[1] = b.x;  z[1] = b.y;
        x[2] = b.z;  y[2] = b.w;  z[2] = c.x;
        x[3] = c.y;  y[3] = c.z;  z[3] = c.w;
        cnt = 4;
    } else {
        cnt = n - base;
        for (int k = 0; k < cnt; ++k) {
            x[k] = q[3 * (base + k) + 0];
            y[k] = q[3 * (base + k) + 1];
            z[k] = q[3 * (base + k) + 2];
        }
    }
    int r[4] = {0, 0, 0, 0};
    #pragma unroll
    for (int k = 0; k < 4; ++k) {
        if (k >= cnt) break;
        int ix, iy, iz;
        if (voxel_of(x[k], y[k], z[k], mnx, mny, mnz, vs, ix, iy, iz))
            r[k] = (int)((grid[ix * GY + iy] >> iz) & 1ull);
    }
    if (cnt == 4) ((int4*)out)[t] = make_int4(r[0], r[1], r[2], r[3]);
    else for (int k = 0; k < cnt; ++k) out[base + k] = r[k];
}

extern "C" void kernel_launch(void* const* d_in, const int* in_sizes, int n_in,
                              void* d_out, int out_size, void* d_ws, size_t ws_size,
                              hipStream_t stream) {
    const float* points = (const float*)d_in[0];
    const float* query  = (const float*)d_in[1];
    const float* aabb   = (const float*)d_in[2];
    const float* vs     = (const float*)d_in[3];
    int* out = (int*)d_out;

    int n_pts = in_sizes[0] / 3;
    int n_q   = in_sizes[1] / 3;
    const int B = 256;
    int n_qt = (n_q + 3) / 4;

    // ws layout: grid(2MB) | dilated(2MB) | buf(15.872MB) | tails(4KB)
    const size_t GRID_B = (size_t)NCOL * 8;
    const size_t BUF_B  = (size_t)TOT_ENTRIES * 2;
    size_t need = 2 * GRID_B + BUF_B + NSEG * 4;   // 19,876,000

    if (ws_size >= need) {
        u64* grid    = (u64*)d_ws;
        u64* dilated = (u64*)((char*)d_ws + GRID_B);
        u16* buf     = (u16*)((char*)d_ws + 2 * GRID_B);
        u32* tails   = (u32*)((char*)d_ws + 2 * GRID_B + BUF_B);

        int nblk_sc = (n_pts + PTS_PER_BLOCK - 1) / PTS_PER_BLOCK;
        zero_tails_kernel<<<1, B, 0, stream>>>(tails);
        scatter_bin_kernel<<<nblk_sc, B, 0, stream>>>(points, n_pts, aabb, vs, buf, tails);
        replay_kernel<<<GX, B, 0, stream>>>(buf, tails, grid);
        dilate_kernel<<<(NCOL + B - 1) / B, B, 0, stream>>>(grid, dilated);
        query4_kernel<<<(n_qt + B - 1) / B, B, 0, stream>>>(query, n_q, aabb, vs, dilated, out);
    } else {
        // fallback: proven atomic path (needs 4 MB)
        u64* grid    = (u64*)d_ws;
        u64* dilated = grid + NCOL;
        zero_grid_kernel<<<(NCOL + B - 1) / B, B, 0, stream>>>(grid, NCOL);
        scatter_atomic_kernel<<<(n_pts + B - 1) / B, B, 0, stream>>>(points, n_pts, aabb, vs, grid);
        dilate_kernel<<<(NCOL + B - 1) / B, B, 0, stream>>>(grid, dilated);
        query4_kernel<<<(n_qt + B - 1) / B, B, 0, stream>>>(query, n_q, aabb, vs, dilated, out);
    }
}